// Round 4
// baseline (42.303 us; speedup 1.0000x reference)
//
#include <hip/hip_runtime.h>
#include <stdint.h>

// Problem constants (from reference)
#define BB 8
#define CC 512
#define NN 4096   // H*W = 64*64
#define HID 24

// async global->LDS, 16B per lane, wave-uniform LDS base + lane*16
#define GLOAD_LDS(gptr, lptr)                                                  \
    __builtin_amdgcn_global_load_lds(                                          \
        (const __attribute__((address_space(1))) void*)(gptr),                 \
        (__attribute__((address_space(3))) void*)(lptr), 16, 0, 0)

// ---------------------------------------------------------------------------
// Kernel 1: g[b,c] = mean_hw(rgb) + mean_hw(chm) + 2/N
// (attention branch == constant 2/N: softmax over spatial axis sums to 1,
//  GAP averages exactly that axis)
//
// Read-path experiment: stage all input bytes via global_load_lds (LDS-DMA,
// no VGPR return) to maximize outstanding reads per CU (5 blocks x 32 KB =
// 160 KB in flight/CU vs ~24 KB with VGPR loads). One block per channel;
// wave w stages slabs [w*4 .. w*4+3] of rgb and chm (1 KB each) and reduces
// ONLY its own slabs -> no barrier between stage and reduce, ordering by the
// wave's own vmcnt(0).
// ---------------------------------------------------------------------------
__global__ __launch_bounds__(256) void gap_kernel(
    const float* __restrict__ rgb,
    const float* __restrict__ chm,
    float* __restrict__ g)
{
    __shared__ float lds[2 * NN];          // 32 KB: [0,4096)=rgb, [4096,8192)=chm
    __shared__ float part[4];

    const int ch   = blockIdx.x;           // 0..4095 (b*C + c)
    const int t    = threadIdx.x;
    const int w    = t >> 6;               // wave 0..3
    const int lane = t & 63;

    const float* rsrc = rgb + (size_t)ch * NN;
    const float* csrc = chm + (size_t)ch * NN;

    // issue 8 x 1KB DMA per wave (4 rgb + 4 chm), all outstanding at once
    #pragma unroll
    for (int j = 0; j < 4; ++j) {
        const int off = (w * 4 + j) * 256;             // float index of slab
        GLOAD_LDS(rsrc + off + lane * 4, &lds[off]);
    }
    #pragma unroll
    for (int j = 0; j < 4; ++j) {
        const int off = (w * 4 + j) * 256;
        GLOAD_LDS(csrc + off + lane * 4, &lds[NN + off]);
    }

    asm volatile("s_waitcnt vmcnt(0)" ::: "memory");

    // wave-private reduce of the 8 KB this wave staged (conflict-free b128)
    const float4* r4 = reinterpret_cast<const float4*>(&lds[w * 1024]);
    const float4* c4 = reinterpret_cast<const float4*>(&lds[NN + w * 1024]);
    float s = 0.f;
    #pragma unroll
    for (int i = 0; i < 4; ++i) {
        float4 a = r4[lane + i * 64];
        float4 b = c4[lane + i * 64];
        s += (a.x + a.y) + (a.z + a.w) + (b.x + b.y) + (b.z + b.w);
    }

    #pragma unroll
    for (int off = 32; off; off >>= 1)
        s += __shfl_down(s, off, 64);

    if (lane == 0) part[w] = s;
    __syncthreads();
    if (t == 0)
        g[ch] = (part[0] + part[1] + part[2] + part[3]) * (1.0f / NN) + 2.0f / NN;
}

// ---------------------------------------------------------------------------
// Kernel 2: tiny MLP.  h1 = relu(g @ w1^T) [8,24]; out = sigmoid(h1 @ w2^T) [8]
// ---------------------------------------------------------------------------
__global__ __launch_bounds__(256) void mlp_kernel(
    const float* __restrict__ g,
    const float* __restrict__ w1,   // [24, 512] row-major
    const float* __restrict__ w2,   // [24]
    float* __restrict__ out)        // [8]
{
    __shared__ float gs[BB * CC];   // 16 KB
    __shared__ float h1[BB][HID];

    const int t = threadIdx.x;
    for (int i = t; i < BB * CC; i += 256) gs[i] = g[i];
    __syncthreads();

    if (t < BB * HID) {
        const int b = t / HID, j = t % HID;
        const float* wrow = w1 + j * CC;
        const float* grow = gs + b * CC;
        float acc = 0.0f;
        #pragma unroll 8
        for (int c = 0; c < CC; ++c) acc = fmaf(grow[c], wrow[c], acc);
        h1[b][j] = acc > 0.0f ? acc : 0.0f;
    }
    __syncthreads();

    if (t < BB) {
        float acc = 0.0f;
        #pragma unroll
        for (int j = 0; j < HID; ++j) acc = fmaf(h1[t][j], w2[j], acc);
        out[t] = 1.0f / (1.0f + expf(-acc));
    }
}

extern "C" void kernel_launch(void* const* d_in, const int* in_sizes, int n_in,
                              void* d_out, int out_size, void* d_ws, size_t ws_size,
                              hipStream_t stream) {
    const float* rgb = (const float*)d_in[0];
    const float* chm = (const float*)d_in[1];
    // d_in[2..5] = qkv weights/biases: provably unused (softmax-mean identity)
    const float* w1  = (const float*)d_in[6];   // [24,512]
    const float* w2  = (const float*)d_in[7];   // [1,24]
    float* out = (float*)d_out;                 // [8]

    float* g = (float*)d_ws;                    // 4096 floats = 16 KB scratch

    gap_kernel<<<BB * CC, 256, 0, stream>>>(rgb, chm, g);
    mlp_kernel<<<1, 256, 0, stream>>>(g, w1, w2, out);
}